// Round 1
// baseline (647.068 us; speedup 1.0000x reference)
//
#include <hip/hip_runtime.h>

#define NN 50000
#define KSEQ 20
#define HN_OFF 6400000   // N*128
#define CN_OFF 12800000  // 2*N*128

using short8 = __attribute__((ext_vector_type(8))) short;
using f32x4  = __attribute__((ext_vector_type(4))) float;

__device__ __forceinline__ unsigned short f2bf(float f) {
    unsigned int u = __float_as_uint(f);
    return (unsigned short)((u + 0x7FFFu + ((u >> 16) & 1u)) >> 16);  // RNE
}
__device__ __forceinline__ float sigf(float x) {
    x = fminf(fmaxf(x, -30.f), 30.f);
    float e = __expf(-x);
    return __fdividef(1.f, 1.f + e);
}
__device__ __forceinline__ float tanh_fast(float x) {
    x = fminf(fmaxf(x, -15.f), 15.f);
    float e = __expf(2.f * x);
    return __fdividef(e - 1.f, e + 1.f);
}

// ---- prep: bf16 weight packs (+transposes) and bias sum ----
__global__ void prep_kernel(const float* __restrict__ Wp, const float* __restrict__ W,
                            const float* __restrict__ Wih, const float* __restrict__ Whh,
                            const float* __restrict__ bih, const float* __restrict__ bhh,
                            unsigned short* __restrict__ Wih_b, unsigned short* __restrict__ Whh_b,
                            unsigned short* __restrict__ Wpt, unsigned short* __restrict__ Wtt,
                            float* __restrict__ bsum) {
    int tid = blockIdx.x * blockDim.x + threadIdx.x;
    if (tid < 65536) { Wih_b[tid] = f2bf(Wih[tid]); return; }
    tid -= 65536;
    if (tid < 65536) { Whh_b[tid] = f2bf(Whh[tid]); return; }
    tid -= 65536;
    if (tid < 32768) { int j = tid >> 8, k = tid & 255; Wpt[tid] = f2bf(Wp[k * 128 + j]); return; }
    tid -= 32768;
    if (tid < 32768) { int j = tid >> 8, k = tid & 255; Wtt[tid] = f2bf(W[k * 128 + j]); return; }
    tid -= 32768;
    if (tid < 512) { bsum[tid] = bih[tid] + bhh[tid]; }
}

// ---- K1: hp = bf16(h @ W_past), 32 rows/block, 8 waves (16 cols each) ----
__global__ __launch_bounds__(512, 2) void hp_kernel(const float* __restrict__ h,
                                                    const unsigned short* __restrict__ Wpt,
                                                    unsigned short* __restrict__ hp_bf) {
    __shared__ __align__(16) unsigned char smem[32 * 512];  // 32 rows x 256 bf16 (swizzled)
    const int tid = threadIdx.x;
    const int w = tid >> 6, l = tid & 63;
    const int l15 = l & 15, lq = l >> 4;
    const int base = blockIdx.x * 32;

    // stage h rows -> bf16 LDS (row = 512B, XOR swizzle (row&7)<<4)
#pragma unroll
    for (int i = 0; i < 4; ++i) {
        int chunk = tid + 512 * i;          // 0..2047 : 32 rows x 64 float4-chunks
        int row = chunk >> 6, kc = chunk & 63;
        int grow = base + row;
        float4 v = make_float4(0.f, 0.f, 0.f, 0.f);
        if (grow < NN) v = *(const float4*)(h + (size_t)grow * 256 + kc * 4);
        ushort4 bv = make_ushort4(f2bf(v.x), f2bf(v.y), f2bf(v.z), f2bf(v.w));
        int off = (row * 512 + kc * 8) ^ ((row & 7) << 4);
        *(ushort4*)(smem + off) = bv;
    }
    __syncthreads();

    const int jb = w * 16 + l15;  // output col
    short8 bf[8];
#pragma unroll
    for (int kt = 0; kt < 8; ++kt)
        bf[kt] = *(const short8*)((const unsigned char*)Wpt + jb * 512 + kt * 64 + lq * 16);

    f32x4 acc[2];
    acc[0] = (f32x4){0.f, 0.f, 0.f, 0.f};
    acc[1] = (f32x4){0.f, 0.f, 0.f, 0.f};
#pragma unroll
    for (int kt = 0; kt < 8; ++kt) {
#pragma unroll
        for (int rt = 0; rt < 2; ++rt) {
            int arow = rt * 16 + l15;
            int off = (arow * 512 + kt * 64 + lq * 16) ^ ((arow & 7) << 4);
            short8 a = *(const short8*)(smem + off);
            acc[rt] = __builtin_amdgcn_mfma_f32_16x16x32_bf16(a, bf[kt], acc[rt], 0, 0, 0);
        }
    }
#pragma unroll
    for (int rt = 0; rt < 2; ++rt)
#pragma unroll
        for (int r = 0; r < 4; ++r) {
            int row = rt * 16 + lq * 4 + r;
            int grow = base + row;
            if (grow < NN) hp_bf[(size_t)grow * 128 + w * 16 + l15] = f2bf(acc[rt][r]);
        }
}

// ---- K2: fused 20-step LSTM + output GEMM. 32 rows/block, 8 waves.
// wave w owns cols w*16..w*16+15 of each gate (i,f,g,o) -> elementwise is lane-local.
__global__ __launch_bounds__(512, 2) void lstm_kernel(const unsigned short* __restrict__ hp_bf,
                                                      const int* __restrict__ agg,
                                                      const unsigned short* __restrict__ Wih_b,
                                                      const unsigned short* __restrict__ Whh_b,
                                                      const unsigned short* __restrict__ Wtt,
                                                      const float* __restrict__ bsum,
                                                      float* __restrict__ out) {
    __shared__ __align__(16) unsigned char xbuf[32 * 256];  // 32 x 128 bf16, swizzled
    __shared__ __align__(16) unsigned char hbuf[32 * 256];
    const int tid = threadIdx.x;
    const int w = tid >> 6, l = tid & 63;
    const int l15 = l & 15, lq = l >> 4;
    const int base = blockIdx.x * 32;

    // persistent B fragments: 4 gates x 8 k-tiles (k<4: W_ih / x, k>=4: W_hh / h)
    short8 bw[4][8];
    float binit[4];
#pragma unroll
    for (int g = 0; g < 4; ++g) {
        int j = g * 128 + w * 16 + l15;
#pragma unroll
        for (int kt = 0; kt < 4; ++kt) {
            bw[g][kt]     = *(const short8*)((const unsigned char*)Wih_b + j * 256 + kt * 64 + lq * 16);
            bw[g][kt + 4] = *(const short8*)((const unsigned char*)Whh_b + j * 256 + kt * 64 + lq * 16);
        }
        binit[g] = bsum[g * 128 + w * 16 + l15];
    }
    // zero h_0
#pragma unroll
    for (int i = 0; i < 4; ++i) *(unsigned int*)(hbuf + tid * 4 + i * 2048) = 0u;

    f32x4 cst[2], hreg[2];
    cst[0] = (f32x4){0.f, 0.f, 0.f, 0.f};
    cst[1] = (f32x4){0.f, 0.f, 0.f, 0.f};
    hreg[0] = cst[0]; hreg[1] = cst[1];

    // gather prefetch for t=0
    const int srow = w * 4 + lq;                 // row this lane stages
    int sgrow = base + srow; if (sgrow >= NN) sgrow = NN - 1;
    uint4 vstage;
    {
        int idx = agg[(size_t)sgrow * KSEQ + 0];
        vstage = *(const uint4*)((const unsigned char*)hp_bf + (size_t)idx * 256 + l15 * 16);
    }
    const int xw_off = (srow * 256 + l15 * 16) ^ ((srow & 7) << 4);

#pragma unroll 1
    for (int t = 0; t < KSEQ; ++t) {
        *(uint4*)(xbuf + xw_off) = vstage;  // x_t into LDS
        __syncthreads();                    // B1: xbuf(t) + hbuf(t) ready

        if (t + 1 < KSEQ) {                 // T14: issue next gather under MFMA phase
            int idx = agg[(size_t)sgrow * KSEQ + (t + 1)];
            vstage = *(const uint4*)((const unsigned char*)hp_bf + (size_t)idx * 256 + l15 * 16);
        }

        f32x4 acc[4][2];
#pragma unroll
        for (int g = 0; g < 4; ++g)
#pragma unroll
            for (int rt = 0; rt < 2; ++rt)
                acc[g][rt] = (f32x4){binit[g], binit[g], binit[g], binit[g]};

#pragma unroll
        for (int kt = 0; kt < 8; ++kt) {
            const unsigned char* buf = (kt < 4) ? xbuf : hbuf;
#pragma unroll
            for (int rt = 0; rt < 2; ++rt) {
                int arow = rt * 16 + l15;
                int off = (arow * 256 + (kt & 3) * 64 + lq * 16) ^ ((arow & 7) << 4);
                short8 a = *(const short8*)(buf + off);
#pragma unroll
                for (int g = 0; g < 4; ++g)
                    acc[g][rt] = __builtin_amdgcn_mfma_f32_16x16x32_bf16(a, bw[g][kt], acc[g][rt], 0, 0, 0);
            }
        }
        __syncthreads();  // B2: all MFMA reads of xbuf/hbuf done

        // lane-local LSTM cell update; write h' (bf16) for next step
#pragma unroll
        for (int rt = 0; rt < 2; ++rt)
#pragma unroll
            for (int r = 0; r < 4; ++r) {
                float iv = acc[0][rt][r], fv = acc[1][rt][r];
                float gv = acc[2][rt][r], ov = acc[3][rt][r];
                float c = sigf(fv) * cst[rt][r] + sigf(iv) * tanh_fast(gv);
                float hv = sigf(ov) * tanh_fast(c);
                cst[rt][r] = c;
                hreg[rt][r] = hv;
                int row = rt * 16 + lq * 4 + r;
                int off = (row * 256 + (w * 16 + l15) * 2) ^ ((row & 7) << 4);
                *(unsigned short*)(hbuf + off) = f2bf(hv);
            }
    }

    // h_n, c_n (fp32, from registers)
#pragma unroll
    for (int rt = 0; rt < 2; ++rt)
#pragma unroll
        for (int r = 0; r < 4; ++r) {
            int row = rt * 16 + lq * 4 + r;
            int grow = base + row;
            if (grow < NN) {
                out[HN_OFF + (size_t)grow * 128 + w * 16 + l15] = hreg[rt][r];
                out[CN_OFF + (size_t)grow * 128 + w * 16 + l15] = cst[rt][r];
            }
        }

    // epilogue: out = elu([hp_row | h_n] @ W). Stage own hp rows into xbuf.
    {
        uint4 v = *(const uint4*)((const unsigned char*)hp_bf + (size_t)sgrow * 256 + l15 * 16);
        *(uint4*)(xbuf + xw_off) = v;
    }
    __syncthreads();  // also covers last hbuf writes

    const int j = w * 16 + l15;  // output col
    short8 bo[8];
#pragma unroll
    for (int kt = 0; kt < 8; ++kt)
        bo[kt] = *(const short8*)((const unsigned char*)Wtt + j * 512 + kt * 64 + lq * 16);

    f32x4 acc2[2];
    acc2[0] = (f32x4){0.f, 0.f, 0.f, 0.f};
    acc2[1] = (f32x4){0.f, 0.f, 0.f, 0.f};
#pragma unroll
    for (int kt = 0; kt < 8; ++kt) {
        const unsigned char* buf = (kt < 4) ? xbuf : hbuf;
#pragma unroll
        for (int rt = 0; rt < 2; ++rt) {
            int arow = rt * 16 + l15;
            int off = (arow * 256 + (kt & 3) * 64 + lq * 16) ^ ((arow & 7) << 4);
            short8 a = *(const short8*)(buf + off);
            acc2[rt] = __builtin_amdgcn_mfma_f32_16x16x32_bf16(a, bo[kt], acc2[rt], 0, 0, 0);
        }
    }
#pragma unroll
    for (int rt = 0; rt < 2; ++rt)
#pragma unroll
        for (int r = 0; r < 4; ++r) {
            int row = rt * 16 + lq * 4 + r;
            int grow = base + row;
            if (grow < NN) {
                float v = acc2[rt][r];
                out[(size_t)grow * 128 + w * 16 + l15] = (v > 0.f) ? v : (__expf(v) - 1.f);
            }
        }
}

extern "C" void kernel_launch(void* const* d_in, const int* in_sizes, int n_in,
                              void* d_out, int out_size, void* d_ws, size_t ws_size,
                              hipStream_t stream) {
    (void)in_sizes; (void)n_in; (void)out_size; (void)ws_size;
    const float* h   = (const float*)d_in[0];
    const int*   agg = (const int*)d_in[1];
    const float* Wp  = (const float*)d_in[2];
    const float* W   = (const float*)d_in[3];
    const float* Wih = (const float*)d_in[4];
    const float* Whh = (const float*)d_in[5];
    const float* bih = (const float*)d_in[6];
    const float* bhh = (const float*)d_in[7];
    float* out = (float*)d_out;

    // ws layout (13.2 MB total)
    unsigned short* hp_bf = (unsigned short*)d_ws;       // 50000*128 bf16
    unsigned short* Wih_b = hp_bf + 6400000;             // 512*128
    unsigned short* Whh_b = Wih_b + 65536;               // 512*128
    unsigned short* Wpt   = Whh_b + 65536;               // 128*256 (W_past^T)
    unsigned short* Wtt   = Wpt + 32768;                 // 128*256 (W^T)
    float*          bsum  = (float*)(Wtt + 32768);       // 512

    prep_kernel<<<771, 256, 0, stream>>>(Wp, W, Wih, Whh, bih, bhh, Wih_b, Whh_b, Wpt, Wtt, bsum);
    hp_kernel<<<1563, 512, 0, stream>>>(h, Wpt, hp_bf);
    lstm_kernel<<<1563, 512, 0, stream>>>(hp_bf, agg, Wih_b, Whh_b, Wtt, bsum, out);
}